// Round 2
// baseline (2709.110 us; speedup 1.0000x reference)
//
#include <hip/hip_runtime.h>
#include <hip/hip_bf16.h>

#define NN 512
#define DEG 8
#define FD 128
#define HD 256
#define MD 256
#define OD 64
#define PD 2
#define HIST 10
#define TOTAL (10 * NN)       /* 5120 queue entries processed */
#define NPAR 648              /* entries with children: i < (TOTAL-S)/8 <= 632 */
#define INV_SQRT_H 0.0625f

typedef __hip_bfloat16 bf16;

// bit-level finite guard (fast-math-proof)
__device__ __forceinline__ float finz(float x) {
  unsigned u = __float_as_uint(x);
  return (((u >> 23) & 0xFFu) == 0xFFu) ? 0.f : x;
}

// runtime-dtype load: bf=1 -> bf16 array, bf=0 -> float array
__device__ __forceinline__ float ldin(const void* p, int idx, int bf) {
  if (bf) return __bfloat162float(((const bf16*)p)[idx]);
  return ((const float*)p)[idx];
}

// ---- scoped-atomic helpers: per-access coherence, NO cache-wide fences ----
// relaxed agent-scope load/store lower to global_load/store with sc1:
// they bypass the (non-cross-XCD-coherent) L2 for this access only, leaving
// the L2-cached weight tables intact. This is the whole point of round 2.
__device__ __forceinline__ float afload(const float* p) {
  return __uint_as_float(__hip_atomic_load((const unsigned*)p, __ATOMIC_RELAXED,
                                           __HIP_MEMORY_SCOPE_AGENT));
}
__device__ __forceinline__ void afstore(float* p, float v) {
  __hip_atomic_store((unsigned*)p, __float_as_uint(v), __ATOMIC_RELAXED,
                     __HIP_MEMORY_SCOPE_AGENT);
}
__device__ __forceinline__ int flagld(const int* p) {
  return __hip_atomic_load(p, __ATOMIC_RELAXED, __HIP_MEMORY_SCOPE_AGENT);
}
__device__ __forceinline__ void flagst(int* p, int v) {
  // release: orders t0's ops; cross-wave ordering comes from the preceding
  // __syncthreads (drains every wave's vmcnt -> sc1 stores are at the
  // coherence point before the flag store issues).
  __hip_atomic_store(p, v, __ATOMIC_RELEASE, __HIP_MEMORY_SCOPE_AGENT);
}

// ---- static device scratch ----
__device__ float g_hist[NN * HIST * HD];    // ring buffers, 5.24 MB
__device__ float g_msgb[NPAR * MD];         // messages of entries with children
__device__ float g_WQK[HD * HD];            // Wq @ Wk^T   (kq = msg.WQK + ck)
__device__ float g_WrS[HD * HD];            // sum of 4 Wr row-blocks
__device__ float g_vq[HD];                  // Wq @ bk
__device__ float g_ck[HD];                  // Wk @ bq
__device__ float g_bqk;                     // bq . bk
__device__ int   g_node[TOTAL];
__device__ int   g_rank[TOTAL];
__device__ int   g_np[TOTAL];               // prev same-node occurrence (-1 none)
__device__ int   g_counts[NN];
__device__ int   g_done[TOTAL];             // 0=pending, 1=hist written, 2=+msg written
__device__ int   g_dtype;                   // 1 = float tensors are bf16
__device__ int   g_i64;                     // 1 = neighbors int64

__device__ __forceinline__ int decode_S(const int* dS) {
  int r = dS[0];
  if (r >= 1 && r <= NN) return r;
  float f = __int_as_float(r);
  if (f >= 1.f && f <= (float)NN) return (int)f;
  unsigned u = ((unsigned)r & 0xFFFFu) << 16;
  float g = __uint_as_float(u);
  if (g >= 1.f && g <= (float)NN) return (int)g;
  return 64;
}

__device__ __forceinline__ int get_nbr(const int* nbrs, int i64, int n, int d) {
  int v = i64 ? nbrs[2 * (n * DEG + d)] : nbrs[n * DEG + d];
  return (v < 0) ? 0 : (v >= NN ? NN - 1 : v);
}

// ---------------- phase A: dtype detect + BFS queue expansion (1 block) ----------------
__global__ void __launch_bounds__(1024)
k_bfs(const unsigned* __restrict__ xa_w, const int* __restrict__ nbrs,
      const int* __restrict__ dS) {
  __shared__ int s_node[TOTAL];              // 20 KB
  __shared__ int s_flags[1];
  const int t = threadIdx.x;
  if (t == 0) {                              // dtype + index-width detection (validated r6)
    int cnt = 0;
    for (int w = 0; w < 64; ++w) {
      unsigned lo = xa_w[w] & 0xFFFFu;
      float av = fabsf(__uint_as_float(lo << 16));
      if (av > 0.000244140625f && av < 64.f) ++cnt;
    }
    g_dtype = (cnt >= 32) ? 1 : 0;
    int allz = 1;
    for (int w = 1; w < 16; w += 2) allz &= (nbrs[w] == 0);
    g_i64 = allz;
    s_flags[0] = allz;
  }
  __syncthreads();
  const int i64 = s_flags[0];
  const int S = decode_S(dS);
  for (int i = t; i < S; i += 1024) s_node[i] = i;
  __syncthreads();
  int done = S;
  while (done < TOTAL) {                     // message tree, depth ~4
    long long nd = (long long)S + 8LL * (long long)done;
    int new_done = nd > (long long)TOTAL ? TOTAL : (int)nd;
    for (int i = done + t; i < new_done; i += 1024)
      s_node[i] = get_nbr(nbrs, i64, s_node[(i - S) >> 3], (i - S) & 7);
    __syncthreads();
    done = new_done;
  }
  for (int i = t; i < TOTAL; i += 1024) g_node[i] = s_node[i];
}

// ---------------- phase B: rank + prev-occurrence, ballot-parallel (512 blocks x 64) ----
// also zeroes the dataflow done-flags (TOTAL == NN*HIST slots, 10 per block)
__global__ void __launch_bounds__(64)
k_rank() {
  const int n = blockIdx.x;                  // node id
  const int l = threadIdx.x;                 // lane
  if (l < HIST) g_done[n * HIST + l] = 0;
  int k = 0, last = -1;
  for (int base = 0; base < TOTAL; base += 64) {
    int nd = g_node[base + l];
    unsigned long long m = __ballot(nd == n);
    if (nd == n) {
      unsigned long long below = m & ((1ull << l) - 1ull);
      g_rank[base + l] = k + (int)__popcll(below);
      g_np[base + l] = below ? (base + 63 - (int)__builtin_clzll(below)) : last;
    }
    if (m) last = base + 63 - (int)__builtin_clzll(m);
    k += (int)__popcll(m);
  }
  if (l == 0) g_counts[n] = k;
}

// ---------------- weights fold + encode (one dispatch, HD+1+NN blocks, split-K 4) -----
__global__ void __launch_bounds__(1024)
k_weights(const void* __restrict__ xa, const void* __restrict__ We,
          const void* __restrict__ be, const void* __restrict__ Wq,
          const void* __restrict__ Wk, const void* __restrict__ Wr,
          const void* __restrict__ bq, const void* __restrict__ bk) {
  const int b = blockIdx.x, t = threadIdx.x;
  const int col = t & 255, grp = t >> 8;
  const int wave = t >> 6, lane = t & 63;
  const int bf = g_dtype;
  __shared__ float sw[HD];
  __shared__ float sp[4][HD];
  __shared__ float sr[16];
  if (b < HD) {
    if (grp == 0) sw[col] = ldin(Wq, b * HD + col, bf);
    __syncthreads();
    {                                            // WQK[b][col], K split 4
      const int h0 = grp * 64;
      float a0 = 0.f, a1 = 0.f, a2 = 0.f, a3 = 0.f;
      for (int h = 0; h < 64; h += 4) {
        a0 += sw[h0 + h]     * ldin(Wk, col * HD + h0 + h,     bf);
        a1 += sw[h0 + h + 1] * ldin(Wk, col * HD + h0 + h + 1, bf);
        a2 += sw[h0 + h + 2] * ldin(Wk, col * HD + h0 + h + 2, bf);
        a3 += sw[h0 + h + 3] * ldin(Wk, col * HD + h0 + h + 3, bf);
      }
      sp[grp][col] = (a0 + a1) + (a2 + a3);
    }
    if (grp == 1) {                              // vq[b] partial (overlapped)
      float pv = sw[col] * ldin(bk, col, bf);
#pragma unroll
      for (int off = 32; off > 0; off >>= 1) pv += __shfl_down(pv, off, 64);
      if (lane == 0) sr[wave] = pv;              // waves 4..7
    }
    if (grp == 2) {                              // WrS row b (overlapped)
      float s = 0.f;
#pragma unroll
      for (int q = 0; q < 4; ++q) s += ldin(Wr, (size_t)(q * HD + b) * HD + col, bf);
      g_WrS[b * HD + col] = s;
    }
    __syncthreads();
    if (grp == 0)
      g_WQK[b * HD + col] = (sp[0][col] + sp[1][col]) + (sp[2][col] + sp[3][col]);
    if (t == 0) g_vq[b] = (sr[4] + sr[5]) + (sr[6] + sr[7]);
  } else if (b == HD) {
    {                                            // ck[col] = Wk row col . bq, split 4
      const int h0 = grp * 64;
      float a0 = 0.f, a1 = 0.f, a2 = 0.f, a3 = 0.f;
      for (int h = 0; h < 64; h += 4) {
        a0 += ldin(Wk, col * HD + h0 + h,     bf) * ldin(bq, h0 + h,     bf);
        a1 += ldin(Wk, col * HD + h0 + h + 1, bf) * ldin(bq, h0 + h + 1, bf);
        a2 += ldin(Wk, col * HD + h0 + h + 2, bf) * ldin(bq, h0 + h + 2, bf);
        a3 += ldin(Wk, col * HD + h0 + h + 3, bf) * ldin(bq, h0 + h + 3, bf);
      }
      sp[grp][col] = (a0 + a1) + (a2 + a3);
    }
    if (grp == 1) {
      float pb = ldin(bq, col, bf) * ldin(bk, col, bf);
#pragma unroll
      for (int off = 32; off > 0; off >>= 1) pb += __shfl_down(pb, off, 64);
      if (lane == 0) sr[wave] = pb;              // waves 4..7
    }
    __syncthreads();
    if (grp == 0)
      g_ck[col] = (sp[0][col] + sp[1][col]) + (sp[2][col] + sp[3][col]);
    if (t == 0) g_bqk = (sr[4] + sr[5]) + (sr[6] + sr[7]);
  } else {                                       // encode node n, K=FD split 4
    const int n = b - HD - 1;
    if (t < FD) sw[t] = ldin(xa, n * FD + t, bf);
    __syncthreads();
    const int f0 = grp * 32;
    float a0 = 0.f, a1 = 0.f, a2 = 0.f, a3 = 0.f;
    for (int f = 0; f < 32; f += 4) {
      a0 += sw[f0 + f]     * ldin(We, (f0 + f)     * HD + col, bf);
      a1 += sw[f0 + f + 1] * ldin(We, (f0 + f + 1) * HD + col, bf);
      a2 += sw[f0 + f + 2] * ldin(We, (f0 + f + 2) * HD + col, bf);
      a3 += sw[f0 + f + 3] * ldin(We, (f0 + f + 3) * HD + col, bf);
    }
    sp[grp][col] = (a0 + a1) + (a2 + a3);
    __syncthreads();
    if (grp == 0)
      g_hist[(size_t)(n * HIST) * HD + col] =
          ldin(be, col, bf) + (sp[0][col] + sp[1][col]) + (sp[2][col] + sp[3][col]);
  }
}

// ---------------- dataflow executor: persistent blocks, fence-free handshake --------
// Block b owns entries b, b+FLOWG, ... (ascending). Deps of entry e are strictly
// smaller indices (prev same-node occurrence, parent (e-S)>>3) -> with all blocks
// resident, the smallest unfinished entry always has its deps done -> progress.
// Co-residency: FLOWG=256 blocks, 1024 thr (16 waves), launch_bounds(1024,1)
// forces VGPR<=128 -> 1 block/CU always fits -> all 256 resident.
// Communication: data via relaxed agent atomics (sc1, cache-bypass per access);
// flag release after __syncthreads-drained stores. NO buffer_inv -> weights stay L2-hot.
#define FLOWG 256
__global__ void __launch_bounds__(1024, 1)
k_flow(const void* __restrict__ fmsg, const void* __restrict__ br_,
       const void* __restrict__ Wm, const void* __restrict__ bm,
       const int* __restrict__ dS) {
  const int t = threadIdx.x;
  const int col = t & 255;
  const int grp = t >> 8;                    // K-slice / j-group: 0..3
  const int wave = t >> 6, lane = t & 63;
  const int S = decode_S(dS);
  const int bf = g_dtype;
  __shared__ float s_msg[MD];
  __shared__ float s_feats[HIST][HD];
  __shared__ float s_p[4][HD];
  __shared__ float s_vals[HD];
  __shared__ float s_ns[HD];
  __shared__ float s_r[16][3];

  for (int e = (int)blockIdx.x; e < TOTAL; e += FLOWG) {
    const int n = g_node[e];
    const int k = g_rank[e];
    const int p = (e >= S) ? ((e - S) >> 3) : 0;
    const bool hc = (S + 8 * e) < TOTAL;
    const int c = k + 1;
    const int v = (c < HIST) ? c : HIST;
    const int slot = c % HIST;

    if (t == 0) {                            // dep wait: hist-ready(1) / msg-ready(2)
      const int prev = g_np[e];
      if (prev >= 0)
        while (flagld(&g_done[prev]) < 1) __builtin_amdgcn_s_sleep(1);
      if (e >= S)
        while (flagld(&g_done[p]) < 2) __builtin_amdgcn_s_sleep(1);
    }
    __syncthreads();                         // deps satisfied for whole block

    if (grp == 0)
      s_msg[col] = (e < S) ? ldin(fmsg, e * MD + col, bf)
                           : finz(afload(&g_msgb[(size_t)p * MD + col]));
    for (int j = grp; j < HIST; j += 4)
      s_feats[j][col] =
          (j < v) ? finz(afload(&g_hist[(size_t)(n * HIST + j) * HD + col])) : 0.f;
    __syncthreads();

    // ---- kq[col] = msg . WQK[:,col] + ck[col], K split 4 ----
    {
      const float* wq = g_WQK + (size_t)(grp * 64) * HD + col;
      const float* mm = s_msg + grp * 64;
      float a0 = 0.f, a1 = 0.f, a2 = 0.f, a3 = 0.f;
      for (int m = 0; m < 64; m += 4) {
        a0 += mm[m]     * wq[(size_t)(m)     * HD];
        a1 += mm[m + 1] * wq[(size_t)(m + 1) * HD];
        a2 += mm[m + 2] * wq[(size_t)(m + 2) * HD];
        a3 += mm[m + 3] * wq[(size_t)(m + 3) * HD];
      }
      s_p[grp][col] = (a0 + a1) + (a2 + a3);
    }
    __syncthreads();
    const float kq =
        g_ck[col] + ((s_p[0][col] + s_p[1][col]) + (s_p[2][col] + s_p[3][col]));

    // ---- 11 dot-products, grp-split: grp g owns j = g, g+4, g+8 (g==2: +msg.vq) ----
    float p0 = s_feats[grp][col] * kq;
    float p1 = s_feats[grp + 4][col] * kq;
    float p2;
    if (grp < 2)       p2 = s_feats[grp + 8][col] * kq;
    else if (grp == 2) p2 = s_msg[col] * g_vq[col];
    else               p2 = 0.f;
#pragma unroll
    for (int off = 32; off > 0; off >>= 1) {
      p0 += __shfl_down(p0, off, 64);
      p1 += __shfl_down(p1, off, 64);
      p2 += __shfl_down(p2, off, 64);
    }
    if (lane == 0) { s_r[wave][0] = p0; s_r[wave][1] = p1; s_r[wave][2] = p2; }
    __syncthreads();

    // every thread folds the 16x3 partials locally (LDS broadcast reads, no extra sync)
    float sc[11];
#pragma unroll
    for (int j = 0; j < 11; ++j) {
      const int g = (j < 10) ? (j & 3) : 2;
      const int i = (j < 10) ? (j >> 2) : 2;
      sc[j] = (s_r[4 * g][i] + s_r[4 * g + 1][i]) + (s_r[4 * g + 2][i] + s_r[4 * g + 3][i]);
    }
    const float bkq = sc[10] + g_bqk;
    float lg[HIST];
#pragma unroll
    for (int j = 0; j < HIST; ++j)
      lg[j] = (j < v) ? ((sc[j] + bkq) * INV_SQRT_H) : -1e30f;
    float mx = lg[0];
#pragma unroll
    for (int j = 1; j < HIST; ++j) mx = fmaxf(mx, lg[j]);
    float e_[HIST], den = 0.f;
#pragma unroll
    for (int j = 0; j < HIST; ++j) { e_[j] = __expf(lg[j] - mx); den += e_[j]; }
    const float iden = 1.0f / den;

    // ---- vals[col] = attn @ feats, same grp-split over j ----
    {
      float vp = e_[grp] * s_feats[grp][col] + e_[grp + 4] * s_feats[grp + 4][col];
      if (grp < 2) vp += e_[grp + 8] * s_feats[grp + 8][col];
      s_p[grp][col] = vp;
    }
    __syncthreads();
    s_vals[col] =
        iden * ((s_p[0][col] + s_p[1][col]) + (s_p[2][col] + s_p[3][col]));  // 4x same value
    __syncthreads();

    // ---- ns = vals @ WrS + br, K split 4 ----
    {
      const float* wr = g_WrS + (size_t)(grp * 64) * HD + col;
      const float* vv = s_vals + grp * 64;
      float a0 = 0.f, a1 = 0.f, a2 = 0.f, a3 = 0.f;
      for (int h = 0; h < 64; h += 4) {
        a0 += vv[h]     * wr[(size_t)(h)     * HD];
        a1 += vv[h + 1] * wr[(size_t)(h + 1) * HD];
        a2 += vv[h + 2] * wr[(size_t)(h + 2) * HD];
        a3 += vv[h + 3] * wr[(size_t)(h + 3) * HD];
      }
      s_p[grp][col] = (a0 + a1) + (a2 + a3);
    }
    __syncthreads();
    const float ns =
        ldin(br_, col, bf) + ((s_p[0][col] + s_p[1][col]) + (s_p[2][col] + s_p[3][col]));
    if (grp == 0) afstore(&g_hist[(size_t)(n * HIST + slot) * HD + col], ns);
    s_ns[col] = ns;                          // 4x same value
    __syncthreads();                         // drains grp0's sc1 stores (vmcnt)
    if (t == 0) flagst(&g_done[e], 1);       // same-node successor may start NOW

    // ---- newmessage = [ns; msg] @ Wm + bm, 512-row K split 4 (children only) ----
    if (hc) {
      const float* src = (grp < 2) ? (s_ns + (grp & 1) * 128) : (s_msg + (grp & 1) * 128);
      const size_t r0 = (size_t)(grp * 128);
      float a0 = 0.f, a1 = 0.f, a2 = 0.f, a3 = 0.f;
      if (bf) {
        const bf16* w = (const bf16*)Wm + r0 * MD + col;
        for (int r = 0; r < 128; r += 4) {
          a0 += src[r]     * __bfloat162float(w[(size_t)(r)     * MD]);
          a1 += src[r + 1] * __bfloat162float(w[(size_t)(r + 1) * MD]);
          a2 += src[r + 2] * __bfloat162float(w[(size_t)(r + 2) * MD]);
          a3 += src[r + 3] * __bfloat162float(w[(size_t)(r + 3) * MD]);
        }
      } else {
        const float* w = (const float*)Wm + r0 * MD + col;
        for (int r = 0; r < 128; r += 4) {
          a0 += src[r]     * w[(size_t)(r)     * MD];
          a1 += src[r + 1] * w[(size_t)(r + 1) * MD];
          a2 += src[r + 2] * w[(size_t)(r + 2) * MD];
          a3 += src[r + 3] * w[(size_t)(r + 3) * MD];
        }
      }
      s_p[grp][col] = (a0 + a1) + (a2 + a3);
    }
    __syncthreads();
    if (hc && grp == 0)
      afstore(&g_msgb[(size_t)e * MD + col],
              ldin(bm, col, bf) +
                  ((s_p[0][col] + s_p[1][col]) + (s_p[2][col] + s_p[3][col])));
    __syncthreads();                         // drains msgb stores
    if (t == 0 && hc) flagst(&g_done[e], 2); // children may start
  }
}

// ---------------- final projection + log_softmax ----------------
__global__ void k_out(const void* __restrict__ Wd, const void* __restrict__ bd,
                      void* __restrict__ out) {
  __shared__ float sf[HD];
  const int b = blockIdx.x;
  const int pp = b >> 9;
  const int n = b & 511;
  const int t = threadIdx.x;                 // 0..63 == O dim
  const int bf = g_dtype;
  int occ = g_counts[n];
  if (occ < 0 || occ > TOTAL) occ = 0;
  const int slot = occ % HIST;               // (count-1)%HIST, count = 1+occ
  for (int h = t; h < HD; h += OD) sf[h] = finz(g_hist[(size_t)(n * HIST + slot) * HD + h]);
  __syncthreads();
  float acc = finz(ldin(bd, pp * OD + t, bf));
  for (int h = 0; h < HD; ++h) acc += sf[h] * ldin(Wd, (pp * HD + h) * OD + t, bf);
  acc = finz(acc);
  float mx = acc;
#pragma unroll
  for (int off = 32; off > 0; off >>= 1) mx = fmaxf(mx, __shfl_xor(mx, off, 64));
  float ex = __expf(acc - mx);
  float s = ex;
#pragma unroll
  for (int off = 32; off > 0; off >>= 1) s += __shfl_xor(s, off, 64);
  float r = finz(acc - mx - logf(s));
  const int oi = (pp * NN + n) * OD + t;
  if (bf) ((bf16*)out)[oi] = __float2bfloat16(r);
  else    ((float*)out)[oi] = r;
}

extern "C" void kernel_launch(void* const* d_in, const int* in_sizes, int n_in,
                              void* d_out, int out_size, void* d_ws, size_t ws_size,
                              hipStream_t stream) {
  const void* xa   = d_in[0];
  const int*  nbrs = (const int*)d_in[1];
  const void* fmsg = d_in[2];
  const void* We   = d_in[3];
  const void* be   = d_in[4];
  const void* Wq   = d_in[5];
  const void* bq   = d_in[6];
  const void* Wk   = d_in[7];
  const void* bk   = d_in[8];
  const void* Wr   = d_in[9];
  const void* br   = d_in[10];
  const void* Wm   = d_in[11];
  const void* bm   = d_in[12];
  const void* Wd   = d_in[13];
  const void* bd   = d_in[14];
  const int*  dS   = (const int*)d_in[15];
  (void)d_ws; (void)ws_size; (void)in_sizes; (void)n_in; (void)out_size;

  k_bfs<<<dim3(1), dim3(1024), 0, stream>>>((const unsigned*)xa, nbrs, dS);
  k_rank<<<dim3(NN), dim3(64), 0, stream>>>();
  k_weights<<<dim3(HD + 1 + NN), dim3(1024), 0, stream>>>(xa, We, be, Wq, Wk, Wr, bq, bk);
  k_flow<<<dim3(FLOWG), dim3(1024), 0, stream>>>(fmsg, br, Wm, bm, dS);
  k_out<<<dim3(PD * NN), dim3(OD), 0, stream>>>(Wd, bd, d_out);
}

// Round 3
// 482.414 us; speedup vs baseline: 5.6157x; 5.6157x over previous
//
#include <hip/hip_runtime.h>
#include <hip/hip_bf16.h>

#define NN 512
#define DEG 8
#define FD 128
#define HD 256
#define MD 256
#define OD 64
#define PD 2
#define HIST 10
#define TOTAL (10 * NN)       /* 5120 queue entries processed */
#define NPAR 648              /* entries with children: i < (TOTAL-S)/8 <= 632 */
#define INV_SQRT_H 0.0625f

typedef __hip_bfloat16 bf16;

// bit-level finite guard (fast-math-proof)
__device__ __forceinline__ float finz(float x) {
  unsigned u = __float_as_uint(x);
  return (((u >> 23) & 0xFFu) == 0xFFu) ? 0.f : x;
}

// runtime-dtype load: bf=1 -> bf16 array, bf=0 -> float array
__device__ __forceinline__ float ldin(const void* p, int idx, int bf) {
  if (bf) return __bfloat162float(((const bf16*)p)[idx]);
  return ((const float*)p)[idx];
}

// device-coherent (L1/L2-bypassing) dword load/store: relaxed atomics lower to a
// single flagged global_load/store_dword — coalesced like any vector load, no fences.
__device__ __forceinline__ float scload(const float* p) {
  return __uint_as_float(__hip_atomic_load((const unsigned*)p, __ATOMIC_RELAXED,
                                           __HIP_MEMORY_SCOPE_AGENT));
}
__device__ __forceinline__ void scstore(float* p, float v) {
  __hip_atomic_store((unsigned*)p, __float_as_uint(v), __ATOMIC_RELAXED,
                     __HIP_MEMORY_SCOPE_AGENT);
}

// ---- static device scratch ----
__device__ float g_hist[NN * HIST * HD];    // slot-0 encoded states + final states
__device__ float g_msgb[NPAR * MD];         // messages of entries with children
__device__ float g_WQK[HD * HD];            // Wq @ Wk^T   (kq = msg.WQK + ck)
__device__ float g_WrS[HD * HD];            // sum of 4 Wr row-blocks
__device__ float g_vq[HD];                  // Wq @ bk
__device__ float g_ck[HD];                  // Wk @ bq
__device__ float g_bqk;                     // bq . bk
__device__ int   g_node[TOTAL];
__device__ int   g_rank[TOTAL];
__device__ int   g_counts[NN];
__device__ int   g_off[NN];                 // CSR offsets (exclusive prefix of counts)
__device__ int   g_list[TOTAL];             // entries sorted by (node, queue index)
__device__ int   g_done[TOTAL];             // message-ready flags (parents only used)
__device__ int   g_dtype;                   // 1 = float tensors are bf16
__device__ int   g_i64;                     // 1 = neighbors int64

__device__ __forceinline__ int decode_S(const int* dS) {
  int r = dS[0];
  if (r >= 1 && r <= NN) return r;
  float f = __int_as_float(r);
  if (f >= 1.f && f <= (float)NN) return (int)f;
  unsigned u = ((unsigned)r & 0xFFFFu) << 16;
  float g = __uint_as_float(u);
  if (g >= 1.f && g <= (float)NN) return (int)g;
  return 64;
}

__device__ __forceinline__ int get_nbr(const int* nbrs, int i64, int n, int d) {
  int v = i64 ? nbrs[2 * (n * DEG + d)] : nbrs[n * DEG + d];
  return (v < 0) ? 0 : (v >= NN ? NN - 1 : v);
}

// ---------------- phase A: dtype detect + BFS queue expansion (1 block) ----------------
__global__ void __launch_bounds__(1024)
k_bfs(const unsigned* __restrict__ xa_w, const int* __restrict__ nbrs,
      const int* __restrict__ dS) {
  __shared__ int s_node[TOTAL];              // 20 KB
  __shared__ int s_flags[1];
  const int t = threadIdx.x;
  if (t == 0) {                              // dtype + index-width detection (validated r6)
    int cnt = 0;
    for (int w = 0; w < 64; ++w) {
      unsigned lo = xa_w[w] & 0xFFFFu;
      float av = fabsf(__uint_as_float(lo << 16));
      if (av > 0.000244140625f && av < 64.f) ++cnt;
    }
    g_dtype = (cnt >= 32) ? 1 : 0;
    int allz = 1;
    for (int w = 1; w < 16; w += 2) allz &= (nbrs[w] == 0);
    g_i64 = allz;
    s_flags[0] = allz;
  }
  __syncthreads();
  const int i64 = s_flags[0];
  const int S = decode_S(dS);
  for (int i = t; i < S; i += 1024) s_node[i] = i;
  __syncthreads();
  int done = S;
  while (done < TOTAL) {                     // message tree, depth ~4
    long long nd = (long long)S + 8LL * (long long)done;
    int new_done = nd > (long long)TOTAL ? TOTAL : (int)nd;
    for (int i = done + t; i < new_done; i += 1024)
      s_node[i] = get_nbr(nbrs, i64, s_node[(i - S) >> 3], (i - S) & 7);
    __syncthreads();
    done = new_done;
  }
  for (int i = t; i < TOTAL; i += 1024) g_node[i] = s_node[i];
}

// ---------------- phase B: rank + counts, ballot-parallel (512 blocks x 64) ----------
// also zeroes the dataflow flags (TOTAL flags, HIST per block)
__global__ void __launch_bounds__(64)
k_rank() {
  const int n = blockIdx.x;                  // node id
  const int l = threadIdx.x;                 // lane
  if (l < HIST) g_done[n * HIST + l] = 0;
  int k = 0;
  for (int base = 0; base < TOTAL; base += 64) {
    int nd = g_node[base + l];
    unsigned long long m = __ballot(nd == n);
    if (nd == n) {
      unsigned long long below = m & ((1ull << l) - 1ull);
      g_rank[base + l] = k + (int)__popcll(below);
    }
    k += (int)__popcll(m);
  }
  if (l == 0) g_counts[n] = k;
}

// ---------------- phase C: CSR build — scan counts + scatter by (node, rank) --------
__global__ void __launch_bounds__(1024)
k_csr() {
  __shared__ int s_sc[NN];                   // inclusive prefix of counts
  const int t = threadIdx.x;
  if (t < NN) s_sc[t] = g_counts[t];
  __syncthreads();
  for (int d = 1; d < NN; d <<= 1) {         // Hillis-Steele, 9 passes
    int v = 0;
    if (t < NN && t >= d) v = s_sc[t - d];
    __syncthreads();
    if (t < NN) s_sc[t] += v;
    __syncthreads();
  }
  if (t < NN) g_off[t] = s_sc[t] - g_counts[t];
  __syncthreads();
  for (int e = t; e < TOTAL; e += 1024) {
    const int n = g_node[e];
    g_list[(s_sc[n] - g_counts[n]) + g_rank[e]] = e;
  }
}

// ---------------- weights fold + encode (one dispatch, HD+1+NN blocks, split-K 4) -----
__global__ void __launch_bounds__(1024)
k_weights(const void* __restrict__ xa, const void* __restrict__ We,
          const void* __restrict__ be, const void* __restrict__ Wq,
          const void* __restrict__ Wk, const void* __restrict__ Wr,
          const void* __restrict__ bq, const void* __restrict__ bk) {
  const int b = blockIdx.x, t = threadIdx.x;
  const int col = t & 255, grp = t >> 8;
  const int wave = t >> 6, lane = t & 63;
  const int bf = g_dtype;
  __shared__ float sw[HD];
  __shared__ float sp[4][HD];
  __shared__ float sr[16];
  if (b < HD) {
    if (grp == 0) sw[col] = ldin(Wq, b * HD + col, bf);
    __syncthreads();
    {                                            // WQK[b][col], K split 4
      const int h0 = grp * 64;
      float a0 = 0.f, a1 = 0.f, a2 = 0.f, a3 = 0.f;
      for (int h = 0; h < 64; h += 4) {
        a0 += sw[h0 + h]     * ldin(Wk, col * HD + h0 + h,     bf);
        a1 += sw[h0 + h + 1] * ldin(Wk, col * HD + h0 + h + 1, bf);
        a2 += sw[h0 + h + 2] * ldin(Wk, col * HD + h0 + h + 2, bf);
        a3 += sw[h0 + h + 3] * ldin(Wk, col * HD + h0 + h + 3, bf);
      }
      sp[grp][col] = (a0 + a1) + (a2 + a3);
    }
    if (grp == 1) {                              // vq[b] partial (overlapped)
      float pv = sw[col] * ldin(bk, col, bf);
#pragma unroll
      for (int off = 32; off > 0; off >>= 1) pv += __shfl_down(pv, off, 64);
      if (lane == 0) sr[wave] = pv;              // waves 4..7
    }
    if (grp == 2) {                              // WrS row b (overlapped)
      float s = 0.f;
#pragma unroll
      for (int q = 0; q < 4; ++q) s += ldin(Wr, (size_t)(q * HD + b) * HD + col, bf);
      g_WrS[b * HD + col] = s;
    }
    __syncthreads();
    if (grp == 0)
      g_WQK[b * HD + col] = (sp[0][col] + sp[1][col]) + (sp[2][col] + sp[3][col]);
    if (t == 0) g_vq[b] = (sr[4] + sr[5]) + (sr[6] + sr[7]);
  } else if (b == HD) {
    {                                            // ck[col] = Wk row col . bq, split 4
      const int h0 = grp * 64;
      float a0 = 0.f, a1 = 0.f, a2 = 0.f, a3 = 0.f;
      for (int h = 0; h < 64; h += 4) {
        a0 += ldin(Wk, col * HD + h0 + h,     bf) * ldin(bq, h0 + h,     bf);
        a1 += ldin(Wk, col * HD + h0 + h + 1, bf) * ldin(bq, h0 + h + 1, bf);
        a2 += ldin(Wk, col * HD + h0 + h + 2, bf) * ldin(bq, h0 + h + 2, bf);
        a3 += ldin(Wk, col * HD + h0 + h + 3, bf) * ldin(bq, h0 + h + 3, bf);
      }
      sp[grp][col] = (a0 + a1) + (a2 + a3);
    }
    if (grp == 1) {
      float pb = ldin(bq, col, bf) * ldin(bk, col, bf);
#pragma unroll
      for (int off = 32; off > 0; off >>= 1) pb += __shfl_down(pb, off, 64);
      if (lane == 0) sr[wave] = pb;              // waves 4..7
    }
    __syncthreads();
    if (grp == 0)
      g_ck[col] = (sp[0][col] + sp[1][col]) + (sp[2][col] + sp[3][col]);
    if (t == 0) g_bqk = (sr[4] + sr[5]) + (sr[6] + sr[7]);
  } else {                                       // encode node n, K=FD split 4
    const int n = b - HD - 1;
    if (t < FD) sw[t] = ldin(xa, n * FD + t, bf);
    __syncthreads();
    const int f0 = grp * 32;
    float a0 = 0.f, a1 = 0.f, a2 = 0.f, a3 = 0.f;
    for (int f = 0; f < 32; f += 4) {
      a0 += sw[f0 + f]     * ldin(We, (f0 + f)     * HD + col, bf);
      a1 += sw[f0 + f + 1] * ldin(We, (f0 + f + 1) * HD + col, bf);
      a2 += sw[f0 + f + 2] * ldin(We, (f0 + f + 2) * HD + col, bf);
      a3 += sw[f0 + f + 3] * ldin(We, (f0 + f + 3) * HD + col, bf);
    }
    sp[grp][col] = (a0 + a1) + (a2 + a3);
    __syncthreads();
    if (grp == 0)
      g_hist[(size_t)(n * HIST) * HD + col] =
          ldin(be, col, bf) + (sp[0][col] + sp[1][col]) + (sp[2][col] + sp[3][col]);
  }
}

// ---------------- dataflow executor: ONE BLOCK PER NODE, LDS-resident history --------
// Block n processes node n's occurrence entries in queue order (g_list CSR).
// Same-node dependency: in-block, in-LDS, zero communication.
// Tree dependency: poll parent's message flag; message passed via sc1 dwords (5 MB total).
// Deadlock-free: entry e's deps have smaller queue index (parent (e-S)>>3 < e; same-node
// predecessors in-block, in-order); 512 blocks, launch_bounds(256,2) => capacity
// 2/CU x 256 CU = 512 => all resident => smallest unfinished entry can always run.
__global__ void __launch_bounds__(256, 2)
k_flow(const void* __restrict__ fmsg, const void* __restrict__ br_,
       const void* __restrict__ Wm, const void* __restrict__ bm,
       const int* __restrict__ dS) {
  const int n = blockIdx.x;
  const int t = threadIdx.x;
  const int wave = t >> 6, lane = t & 63;
  const int S = decode_S(dS);
  const int bf = g_dtype;
  __shared__ float s_hist[HIST][HD];         // node-n ring buffer, column t private
  __shared__ float s_msg[MD];
  __shared__ float s_vals[HD];
  __shared__ float s_ns[HD];
  __shared__ float s_red[4][HIST + 1];
  const int cnt = g_counts[n];
  const int off = g_off[n];
#pragma unroll
  for (int j = 1; j < HIST; ++j) s_hist[j][t] = 0.f;   // invalid slots read as 0 (masked)
  s_hist[0][t] = finz(g_hist[(size_t)n * HIST * HD + t]);  // encoded (cross-dispatch, plain)
  __syncthreads();

  for (int k = 0; k < cnt; ++k) {
    const int e = g_list[off + k];
    const int c = k + 1;
    const int v = (c < HIST) ? c : HIST;
    const int slot = c % HIST;
    const bool hc = (S + 8 * e) < TOTAL;

    // ---- acquire message ----
    float ms;
    if (e < S) {
      ms = ldin(fmsg, e * MD + t, bf);
    } else {
      const int p = (e - S) >> 3;
      if (t == 0)
        while (__hip_atomic_load(&g_done[p], __ATOMIC_RELAXED,
                                 __HIP_MEMORY_SCOPE_AGENT) == 0)
          __builtin_amdgcn_s_sleep(4);
      __syncthreads();                       // flag seen by whole block
      ms = scload(g_msgb + (size_t)p * MD + t);
    }
    s_msg[t] = finz(ms);
    __syncthreads();

    // ---- kq[t] = msg . WQK[:,t] + ck[t] (4-acc) ----
    float a0 = 0.f, a1 = 0.f, a2 = 0.f, a3 = 0.f;
    for (int m = 0; m < MD; m += 4) {
      a0 += s_msg[m]     * g_WQK[(m)     * HD + t];
      a1 += s_msg[m + 1] * g_WQK[(m + 1) * HD + t];
      a2 += s_msg[m + 2] * g_WQK[(m + 2) * HD + t];
      a3 += s_msg[m + 3] * g_WQK[(m + 3) * HD + t];
    }
    const float kq = g_ck[t] + ((a0 + a1) + (a2 + a3));

    // ---- 11 dot-products via wave shuffle + LDS fold ----
    float part[HIST + 1];
#pragma unroll
    for (int j = 0; j < HIST; ++j) part[j] = s_hist[j][t] * kq;
    part[HIST] = s_msg[t] * g_vq[t];
#pragma unroll
    for (int o = 32; o > 0; o >>= 1) {
#pragma unroll
      for (int j = 0; j <= HIST; ++j) part[j] += __shfl_down(part[j], o, 64);
    }
    if (lane == 0) {
#pragma unroll
      for (int j = 0; j <= HIST; ++j) s_red[wave][j] = part[j];
    }
    __syncthreads();

    float sc[HIST + 1];
#pragma unroll
    for (int j = 0; j <= HIST; ++j)
      sc[j] = (s_red[0][j] + s_red[1][j]) + (s_red[2][j] + s_red[3][j]);
    const float bkq = sc[HIST] + g_bqk;
    float lg[HIST];
#pragma unroll
    for (int j = 0; j < HIST; ++j)
      lg[j] = (j < v) ? ((sc[j] + bkq) * INV_SQRT_H) : -1e30f;
    float mx = lg[0];
#pragma unroll
    for (int j = 1; j < HIST; ++j) mx = fmaxf(mx, lg[j]);
    float e_[HIST], den = 0.f;
#pragma unroll
    for (int j = 0; j < HIST; ++j) { e_[j] = __expf(lg[j] - mx); den += e_[j]; }
    const float iden = 1.0f / den;
    float val = 0.f;
#pragma unroll
    for (int j = 0; j < HIST; ++j) val += e_[j] * s_hist[j][t];
    s_vals[t] = val * iden;
    __syncthreads();

    // ---- ns = vals @ WrS + br ----
    float b0 = 0.f, b1 = 0.f, b2 = 0.f, b3 = 0.f;
    for (int h = 0; h < HD; h += 4) {
      b0 += s_vals[h]     * g_WrS[(h)     * HD + t];
      b1 += s_vals[h + 1] * g_WrS[(h + 1) * HD + t];
      b2 += s_vals[h + 2] * g_WrS[(h + 2) * HD + t];
      b3 += s_vals[h + 3] * g_WrS[(h + 3) * HD + t];
    }
    const float ns = ldin(br_, t, bf) + ((b0 + b1) + (b2 + b3));
    s_hist[slot][t] = ns;                    // column-private: no sync needed for s_hist
    if (k == cnt - 1)                        // final state for k_out (slot == occ%HIST)
      g_hist[(size_t)(n * HIST + slot) * HD + t] = ns;
    if (hc) s_ns[t] = ns;
    __syncthreads();

    // ---- newmessage = [ns; msg] @ Wm + bm (parents only) ----
    if (hc) {
      float c0 = 0.f, c1 = 0.f, c2 = 0.f, c3 = 0.f;
      if (bf) {
        const bf16* w = (const bf16*)Wm;
        for (int h = 0; h < HD; h += 4) {
          c0 += s_ns[h]     * __bfloat162float(w[(h)     * MD + t]);
          c1 += s_ns[h + 1] * __bfloat162float(w[(h + 1) * MD + t]);
          c2 += s_ns[h + 2] * __bfloat162float(w[(h + 2) * MD + t]);
          c3 += s_ns[h + 3] * __bfloat162float(w[(h + 3) * MD + t]);
        }
        for (int m = 0; m < MD; m += 4) {
          c0 += s_msg[m]     * __bfloat162float(w[(HD + m)     * MD + t]);
          c1 += s_msg[m + 1] * __bfloat162float(w[(HD + m + 1) * MD + t]);
          c2 += s_msg[m + 2] * __bfloat162float(w[(HD + m + 2) * MD + t]);
          c3 += s_msg[m + 3] * __bfloat162float(w[(HD + m + 3) * MD + t]);
        }
      } else {
        const float* w = (const float*)Wm;
        for (int h = 0; h < HD; h += 4) {
          c0 += s_ns[h]     * w[(h)     * MD + t];
          c1 += s_ns[h + 1] * w[(h + 1) * MD + t];
          c2 += s_ns[h + 2] * w[(h + 2) * MD + t];
          c3 += s_ns[h + 3] * w[(h + 3) * MD + t];
        }
        for (int m = 0; m < MD; m += 4) {
          c0 += s_msg[m]     * w[(HD + m)     * MD + t];
          c1 += s_msg[m + 1] * w[(HD + m + 1) * MD + t];
          c2 += s_msg[m + 2] * w[(HD + m + 2) * MD + t];
          c3 += s_msg[m + 3] * w[(HD + m + 3) * MD + t];
        }
      }
      scstore(&g_msgb[(size_t)e * MD + t],
              ldin(bm, t, bf) + ((c0 + c1) + (c2 + c3)));
      asm volatile("s_waitcnt vmcnt(0)" ::: "memory");   // own stores at coherence point
    }
    __syncthreads();                         // all waves' stores drained + s_msg free
    if (hc && t == 0)
      __hip_atomic_store(&g_done[e], 1, __ATOMIC_RELAXED,
                         __HIP_MEMORY_SCOPE_AGENT);
  }
}

// ---------------- final projection + log_softmax ----------------
__global__ void k_out(const void* __restrict__ Wd, const void* __restrict__ bd,
                      void* __restrict__ out) {
  __shared__ float sf[HD];
  const int b = blockIdx.x;
  const int pp = b >> 9;
  const int n = b & 511;
  const int t = threadIdx.x;                 // 0..63 == O dim
  const int bf = g_dtype;
  int occ = g_counts[n];
  if (occ < 0 || occ > TOTAL) occ = 0;
  const int slot = occ % HIST;               // (count-1)%HIST, count = 1+occ
  for (int h = t; h < HD; h += OD) sf[h] = finz(g_hist[(size_t)(n * HIST + slot) * HD + h]);
  __syncthreads();
  float acc = finz(ldin(bd, pp * OD + t, bf));
  for (int h = 0; h < HD; ++h) acc += sf[h] * ldin(Wd, (pp * HD + h) * OD + t, bf);
  acc = finz(acc);
  float mx = acc;
#pragma unroll
  for (int off = 32; off > 0; off >>= 1) mx = fmaxf(mx, __shfl_xor(mx, off, 64));
  float ex = __expf(acc - mx);
  float s = ex;
#pragma unroll
  for (int off = 32; off > 0; off >>= 1) s += __shfl_xor(s, off, 64);
  float r = finz(acc - mx - logf(s));
  const int oi = (pp * NN + n) * OD + t;
  if (bf) ((bf16*)out)[oi] = __float2bfloat16(r);
  else    ((float*)out)[oi] = r;
}

extern "C" void kernel_launch(void* const* d_in, const int* in_sizes, int n_in,
                              void* d_out, int out_size, void* d_ws, size_t ws_size,
                              hipStream_t stream) {
  const void* xa   = d_in[0];
  const int*  nbrs = (const int*)d_in[1];
  const void* fmsg = d_in[2];
  const void* We   = d_in[3];
  const void* be   = d_in[4];
  const void* Wq   = d_in[5];
  const void* bq   = d_in[6];
  const void* Wk   = d_in[7];
  const void* bk   = d_in[8];
  const void* Wr   = d_in[9];
  const void* br   = d_in[10];
  const void* Wm   = d_in[11];
  const void* bm   = d_in[12];
  const void* Wd   = d_in[13];
  const void* bd   = d_in[14];
  const int*  dS   = (const int*)d_in[15];
  (void)d_ws; (void)ws_size; (void)in_sizes; (void)n_in; (void)out_size;

  k_bfs<<<dim3(1), dim3(1024), 0, stream>>>((const unsigned*)xa, nbrs, dS);
  k_rank<<<dim3(NN), dim3(64), 0, stream>>>();
  k_csr<<<dim3(1), dim3(1024), 0, stream>>>();
  k_weights<<<dim3(HD + 1 + NN), dim3(1024), 0, stream>>>(xa, We, be, Wq, Wk, Wr, bq, bk);
  k_flow<<<dim3(NN), dim3(256), 0, stream>>>(fmsg, br, Wm, bm, dS);
  k_out<<<dim3(PD * NN), dim3(OD), 0, stream>>>(Wd, bd, d_out);
}